// Round 13
// baseline (520.107 us; speedup 1.0000x reference)
//
#include <hip/hip_runtime.h>
#include <hip/hip_bf16.h>
#include <math.h>

#define N_IMG 4
#define CIN 512
#define NANCH 36864          // 64*64*9
#define PRE_NMS_N 3000
#define POST_NMS_N 300
#define NWORD 47             // ceil(3000/64)
#define NPAIR 1128           // NWORD*(NWORD+1)/2
#define PPX 4356             // 66*66 padded pixels

// out layout (floats)
#define OFF_SCORES 589824
#define OFF_ROIS   884736
#define OFF_VALID  889536
#define OFF_ANCH   890736

typedef _Float16 f16x8 __attribute__((ext_vector_type(8)));
typedef float f32x4 __attribute__((ext_vector_type(4)));

__device__ __forceinline__ int swz(int p) { return (p + (p >> 2)) & 3; }

__device__ __forceinline__ unsigned long long rdlane64(unsigned long long v, int l) {
  unsigned int lo = (unsigned int)__builtin_amdgcn_readlane((int)(unsigned int)v, l);
  unsigned int hi = (unsigned int)__builtin_amdgcn_readlane((int)(unsigned int)(v >> 32), l);
  return (((unsigned long long)hi) << 32) | lo;
}

// direct global->LDS 16B copy (gfx950); dest = wave-uniform base + lane*16 (linear).
__device__ __forceinline__ void gl_lds16(const void* g, void* l) {
  __builtin_amdgcn_global_load_lds(
      (const __attribute__((address_space(1))) unsigned int*)g,
      (__attribute__((address_space(3))) unsigned int*)l, 16, 0, 0);
}

// ---------------- K0wh: W1 split (x64) + head-weight split (x64), fused launch --------
__global__ __launch_bounds__(256) void k0wh_convert(
    const float* __restrict__ W1, _Float16* __restrict__ wth, _Float16* __restrict__ wtl,
    const float* __restrict__ Wl, const float* __restrict__ Ws,
    _Float16* __restrict__ whdh, _Float16* __restrict__ whdl) {
  const int bx = blockIdx.x;
  if (bx < 144) {
    const int tap = bx % 9, co0 = (bx / 9) * 32;
    for (int idx = threadIdx.x; idx < 32 * 512; idx += 256) {
      int col = idx >> 9, ci = idx & 511;
      float v = W1[(size_t)(co0 + col) * 4608 + ci * 9 + tap] * 64.0f;
      _Float16 hi = (_Float16)v;
      float lo = v - (float)hi;
      size_t o = ((size_t)(tap * 512 + co0 + col) << 9) + ci;
      wth[o] = hi; wtl[o] = (_Float16)lo;
    }
  } else {
    int idx = (bx - 144) * 256 + threadIdx.x;
    if (idx < 64 * 512) {
      int ch = idx >> 9, k = idx & 511;
      float v = 0.f;
      if (ch < 36) v = Wl[ch * 512 + k];
      else if (ch < 54) v = Ws[(ch - 36) * 512 + k];
      v *= 64.0f;
      _Float16 hi = (_Float16)v;
      float lo = v - (float)hi;
      whdh[idx] = hi; whdl[idx] = (_Float16)lo;
    }
  }
}

// ---------------- K0x: x [ci][64x64] -> padded xh/xl [img_l][66*66][512] f16 split ----
__global__ __launch_bounds__(256) void k0x_convert(
    const float* __restrict__ x, _Float16* __restrict__ xh, _Float16* __restrict__ xl,
    int img0) {
  const int bx = blockIdx.x, ci0 = blockIdx.y * 64;
  const int img_l = blockIdx.z;
  const int img = img0 + img_l;
  const size_t sbase = (size_t)img_l * PPX;
  const int tid = threadIdx.x;
  if (bx < 64) {
    __shared__ float t[64][65];
    const float* xp = x + ((size_t)img * 512 + ci0) * 4096 + bx * 64;
    for (int idx = tid; idx < 4096; idx += 256) {
      int ci_l = idx >> 6, col = idx & 63;
      t[ci_l][col] = xp[(size_t)ci_l * 4096 + col];
    }
    __syncthreads();
    for (int idx = tid; idx < 4096; idx += 256) {
      int col = idx >> 6, ci_l = idx & 63;
      float v = t[ci_l][col];
      _Float16 hi = (_Float16)v;
      float lo = v - (float)hi;
      size_t o = ((sbase + (size_t)(bx + 1) * 66 + col + 1) << 9) + ci0 + ci_l;
      xh[o] = hi; xl[o] = (_Float16)lo;
    }
  } else {
    for (int tt = tid; tt < 52 * 64; tt += 256) {
      int pl = tt >> 6, ci_l = tt & 63;
      int p = (bx - 64) * 52 + pl;
      if (p < 260) {
        int pp;
        if (p < 66) pp = p;
        else if (p < 132) pp = 65 * 66 + (p - 66);
        else if (p < 196) pp = (p - 132 + 1) * 66;
        else pp = (p - 196 + 1) * 66 + 65;
        size_t o = ((sbase + pp) << 9) + ci0 + ci_l;
        xh[o] = (_Float16)0.f; xl[o] = (_Float16)0.f;
      }
    }
  }
}

// ---------------- K1: conv3x3 MFMA implicit GEMM, 128x128 block tile ------------------
// R11: the R0 verified form (merged K, register staging, LDS-write after MFMA, dist-1
// prefetch). Both alternatives HW-refuted: R3 global-B fragments (352us), R10
// global_load_lds staging (322us). Measured local optimum: ~251us, MfmaUtil ~42.7%.
__global__ __launch_bounds__(256, 2) void k1_gemm(
    const _Float16* __restrict__ xh, const _Float16* __restrict__ xl,
    const _Float16* __restrict__ wth, const _Float16* __restrict__ wtl,
    const float* __restrict__ b1, float* __restrict__ h_out) {
  const int tid = threadIdx.x;
  const int co0 = blockIdx.x * 128;
  const int px0 = blockIdx.y * 128;          // linear px across nipp images
  const int img_l = px0 >> 12;
  const int y0 = (px0 & 4095) >> 6;

  __shared__ __align__(16) _Float16 AsL[4][4096];   // [buf*2+hl][128px x 32ci]
  __shared__ __align__(16) _Float16 BsL[4][4096];   // [buf*2+hl][128co x 32ci]

  const int lane = tid & 63, q = lane >> 4, lr = lane & 15;
  const int wid = tid >> 6, wm = wid & 1, wn = wid >> 1;

  int abase[2], bbase[2];
  #pragma unroll
  for (int it = 0; it < 2; ++it) {
    int s = it * 256 + tid;
    int pxl = s >> 2, cpos = s & 3;
    int c = cpos ^ swz(pxl);
    int row = pxl >> 6, xcol = pxl & 63;
    abase[it] = ((img_l * PPX + (y0 + row) * 66 + xcol) << 9) + c * 8;
    int bcol = s >> 2;
    int bc = (s & 3) ^ swz(bcol);
    bbase[it] = ((co0 + bcol) << 9) + bc * 8;
  }

  const int DD[9] = {0, 1, 2, 66, 67, 68, 132, 133, 134};

  f32x4 acc[4][4] = {};
  float4 rah[2], ral[2], rbh[2], rbl[2];

  #pragma unroll
  for (int it = 0; it < 2; ++it) {
    rah[it] = *(const float4*)(xh + abase[it]);
    ral[it] = *(const float4*)(xl + abase[it]);
    rbh[it] = *(const float4*)(wth + bbase[it]);
    rbl[it] = *(const float4*)(wtl + bbase[it]);
  }
  #pragma unroll
  for (int it = 0; it < 2; ++it) {
    *(float4*)&AsL[0][(it * 256 + tid) * 8] = rah[it];
    *(float4*)&AsL[1][(it * 256 + tid) * 8] = ral[it];
    *(float4*)&BsL[0][(it * 256 + tid) * 8] = rbh[it];
    *(float4*)&BsL[1][(it * 256 + tid) * 8] = rbl[it];
  }

  int tap = 0, cb = 0;   // tap fastest (cb-outer)
  for (int t = 0; t < 144; ++t) {
    __syncthreads();
    const int buf = t & 1;
    if (t < 143) {
      int tapn = tap + 1, cbn = cb;
      if (tapn == 9) { tapn = 0; cbn = cb + 1; }
      int ad = (DD[tapn] << 9) + cbn * 32;
      int bd = tapn * 262144 + cbn * 32;
      #pragma unroll
      for (int it = 0; it < 2; ++it) {
        rah[it] = *(const float4*)(xh + abase[it] + ad);
        ral[it] = *(const float4*)(xl + abase[it] + ad);
        rbh[it] = *(const float4*)(wth + bbase[it] + bd);
        rbl[it] = *(const float4*)(wtl + bbase[it] + bd);
      }
    }
    f16x8 ah[4], al[4], bh[4], bl[4];
    #pragma unroll
    for (int mi = 0; mi < 4; ++mi) {
      int pxl = wm * 64 + mi * 16 + lr;
      int cpr = q ^ swz(pxl);
      ah[mi] = *(const f16x8*)&AsL[buf * 2 + 0][pxl * 32 + cpr * 8];
      al[mi] = *(const f16x8*)&AsL[buf * 2 + 1][pxl * 32 + cpr * 8];
    }
    #pragma unroll
    for (int ni = 0; ni < 4; ++ni) {
      int col = wn * 64 + ni * 16 + lr;
      int cpr = q ^ swz(col);
      bh[ni] = *(const f16x8*)&BsL[buf * 2 + 0][col * 32 + cpr * 8];
      bl[ni] = *(const f16x8*)&BsL[buf * 2 + 1][col * 32 + cpr * 8];
    }
    #pragma unroll
    for (int mi = 0; mi < 4; ++mi)
      #pragma unroll
      for (int ni = 0; ni < 4; ++ni) {
        acc[mi][ni] = __builtin_amdgcn_mfma_f32_16x16x32_f16(ah[mi], bh[ni], acc[mi][ni], 0, 0, 0);
        acc[mi][ni] = __builtin_amdgcn_mfma_f32_16x16x32_f16(ah[mi], bl[ni], acc[mi][ni], 0, 0, 0);
        acc[mi][ni] = __builtin_amdgcn_mfma_f32_16x16x32_f16(al[mi], bh[ni], acc[mi][ni], 0, 0, 0);
      }
    if (t < 143) {
      int nb = (t + 1) & 1;
      #pragma unroll
      for (int it = 0; it < 2; ++it) {
        *(float4*)&AsL[nb * 2 + 0][(it * 256 + tid) * 8] = rah[it];
        *(float4*)&AsL[nb * 2 + 1][(it * 256 + tid) * 8] = ral[it];
        *(float4*)&BsL[nb * 2 + 0][(it * 256 + tid) * 8] = rbh[it];
        *(float4*)&BsL[nb * 2 + 1][(it * 256 + tid) * 8] = rbl[it];
      }
    }
    ++tap;
    if (tap == 9) { tap = 0; ++cb; }
  }

  float bb[4];
  #pragma unroll
  for (int ni = 0; ni < 4; ++ni) bb[ni] = b1[co0 + wn * 64 + ni * 16 + lr];
  #pragma unroll
  for (int mi = 0; mi < 4; ++mi)
    #pragma unroll
    for (int ni = 0; ni < 4; ++ni)
      #pragma unroll
      for (int rr = 0; rr < 4; ++rr) {
        int pxl = wm * 64 + mi * 16 + q * 4 + rr;
        int co = co0 + wn * 64 + ni * 16 + lr;
        float v = acc[mi][ni][rr] * 0.015625f + bb[ni];
        h_out[((size_t)(px0 + pxl) << 9) + co] = fmaxf(v, 0.f);
      }
}

// ---------------- K2m: heads as MFMA implicit GEMM + fused decode (R8) ----------------
__global__ __launch_bounds__(256, 1) void k2m_heads(
    const float* __restrict__ h,
    const _Float16* __restrict__ whdh, const _Float16* __restrict__ whdl,
    const float* __restrict__ bl, const float* __restrict__ bs,
    float* __restrict__ rpn_locs, float* __restrict__ rpn_scores,
    int img0, const int* __restrict__ ihp, const int* __restrict__ iwp,
    float* __restrict__ anchors_out, float4* __restrict__ boxes,
    unsigned long long* __restrict__ keys) {
  const int tid = threadIdx.x;
  const int px0 = blockIdx.x * 128;          // linear px across nipp images

  __shared__ __align__(16) _Float16 As[4][4096];   // [buf*2+hl][128px x 32k]
  __shared__ __align__(16) _Float16 Bs[4][2048];   // [buf*2+hl][64ch x 32k]
  __shared__ float Cs[128][68];                    // +4 pad

  const int lane = tid & 63, q = lane >> 4, lr = lane & 15;
  const int wid = tid >> 6, wm = wid & 1, wn = wid >> 1;

  int apx[2], ac[2];
  #pragma unroll
  for (int it = 0; it < 2; ++it) {
    int s = it * 256 + tid;
    apx[it] = s >> 2;
    ac[it] = (s & 3) ^ swz(s >> 2);
  }
  const int bcol = tid >> 2, bc = (tid & 3) ^ swz(tid >> 2);

  f32x4 acc[4][2] = {};
  f16x8 rahh[2], rahl[2], rbhh, rbhl;

  // prologue: tile 0
  #pragma unroll
  for (int it = 0; it < 2; ++it) {
    const float* src = h + ((size_t)(px0 + apx[it]) << 9) + ac[it] * 8;
    float4 v0 = *(const float4*)(src);
    float4 v1 = *(const float4*)(src + 4);
    float vv[8] = {v0.x, v0.y, v0.z, v0.w, v1.x, v1.y, v1.z, v1.w};
    f16x8 hi8, lo8;
    #pragma unroll
    for (int e = 0; e < 8; ++e) {
      _Float16 hh = (_Float16)vv[e];
      hi8[e] = hh; lo8[e] = (_Float16)(vv[e] - (float)hh);
    }
    rahh[it] = hi8; rahl[it] = lo8;
  }
  rbhh = *(const f16x8*)(whdh + bcol * 512 + bc * 8);
  rbhl = *(const f16x8*)(whdl + bcol * 512 + bc * 8);
  #pragma unroll
  for (int it = 0; it < 2; ++it) {
    *(f16x8*)&As[0][(it * 256 + tid) * 8] = rahh[it];
    *(f16x8*)&As[1][(it * 256 + tid) * 8] = rahl[it];
  }
  *(f16x8*)&Bs[0][tid * 8] = rbhh;
  *(f16x8*)&Bs[1][tid * 8] = rbhl;

  for (int t = 0; t < 16; ++t) {
    __syncthreads();
    const int buf = t & 1;
    if (t < 15) {
      const int kn = (t + 1) * 32;
      #pragma unroll
      for (int it = 0; it < 2; ++it) {
        const float* src = h + ((size_t)(px0 + apx[it]) << 9) + kn + ac[it] * 8;
        float4 v0 = *(const float4*)(src);
        float4 v1 = *(const float4*)(src + 4);
        float vv[8] = {v0.x, v0.y, v0.z, v0.w, v1.x, v1.y, v1.z, v1.w};
        f16x8 hi8, lo8;
        #pragma unroll
        for (int e = 0; e < 8; ++e) {
          _Float16 hh = (_Float16)vv[e];
          hi8[e] = hh; lo8[e] = (_Float16)(vv[e] - (float)hh);
        }
        rahh[it] = hi8; rahl[it] = lo8;
      }
      rbhh = *(const f16x8*)(whdh + bcol * 512 + kn + bc * 8);
      rbhl = *(const f16x8*)(whdl + bcol * 512 + kn + bc * 8);
    }
    f16x8 ah[4], al[4], bh[2], blo[2];
    #pragma unroll
    for (int mi = 0; mi < 4; ++mi) {
      int pxl = wm * 64 + mi * 16 + lr;
      int cpr = q ^ swz(pxl);
      ah[mi] = *(const f16x8*)&As[buf * 2 + 0][pxl * 32 + cpr * 8];
      al[mi] = *(const f16x8*)&As[buf * 2 + 1][pxl * 32 + cpr * 8];
    }
    #pragma unroll
    for (int ni = 0; ni < 2; ++ni) {
      int col = wn * 32 + ni * 16 + lr;
      int cpr = q ^ swz(col);
      bh[ni]  = *(const f16x8*)&Bs[buf * 2 + 0][col * 32 + cpr * 8];
      blo[ni] = *(const f16x8*)&Bs[buf * 2 + 1][col * 32 + cpr * 8];
    }
    #pragma unroll
    for (int mi = 0; mi < 4; ++mi)
      #pragma unroll
      for (int ni = 0; ni < 2; ++ni) {
        acc[mi][ni] = __builtin_amdgcn_mfma_f32_16x16x32_f16(ah[mi], bh[ni],  acc[mi][ni], 0, 0, 0);
        acc[mi][ni] = __builtin_amdgcn_mfma_f32_16x16x32_f16(ah[mi], blo[ni], acc[mi][ni], 0, 0, 0);
        acc[mi][ni] = __builtin_amdgcn_mfma_f32_16x16x32_f16(al[mi], bh[ni],  acc[mi][ni], 0, 0, 0);
      }
    if (t < 15) {
      int nb = (t + 1) & 1;
      #pragma unroll
      for (int it = 0; it < 2; ++it) {
        *(f16x8*)&As[nb * 2 + 0][(it * 256 + tid) * 8] = rahh[it];
        *(f16x8*)&As[nb * 2 + 1][(it * 256 + tid) * 8] = rahl[it];
      }
      *(f16x8*)&Bs[nb * 2 + 0][tid * 8] = rbhh;
      *(f16x8*)&Bs[nb * 2 + 1][tid * 8] = rbhl;
    }
  }

  // C tile -> LDS with /64 + bias
  #pragma unroll
  for (int mi = 0; mi < 4; ++mi)
    #pragma unroll
    for (int ni = 0; ni < 2; ++ni) {
      int ch = wn * 32 + ni * 16 + lr;
      float bias = (ch < 36) ? bl[ch] : ((ch < 54) ? bs[ch - 36] : 0.f);
      #pragma unroll
      for (int rr = 0; rr < 4; ++rr) {
        int pxl = wm * 64 + mi * 16 + q * 4 + rr;
        Cs[pxl][ch] = acc[mi][ni][rr] * 0.015625f + bias;
      }
    }
  __syncthreads();

  // fused decode epilogue: 128 px x 9 anchors (verbatim math from old k2)
  const float imh = (float)ihp[0], imw = (float)iwp[0];
  const float ratios[3] = {0.5f, 1.0f, 2.0f};
  const float scales[3] = {8.f, 16.f, 32.f};
  for (int t2 = tid; t2 < 128 * 9; t2 += 256) {
    int px_l = t2 / 9, a = t2 - px_l * 9;
    int pxg = px0 + px_l;
    int img = img0 + (pxg >> 12);
    int p_loc = pxg & 4095;
    size_t abase = (size_t)img * NANCH + (size_t)p_loc * 9;
    int yy = p_loc >> 6, xx = p_loc & 63;

    float4 lv; lv.x = Cs[px_l][4 * a]; lv.y = Cs[px_l][4 * a + 1];
    lv.z = Cs[px_l][4 * a + 2]; lv.w = Cs[px_l][4 * a + 3];
    *(float4*)(rpn_locs + (abase + a) * 4) = lv;
    float s0 = Cs[px_l][36 + 2 * a], s1 = Cs[px_l][36 + 2 * a + 1];
    float2 sv; sv.x = s0; sv.y = s1;
    *(float2*)(rpn_scores + (abase + a) * 2) = sv;
    float m = fmaxf(s0, s1);
    float e0 = expf(s0 - m), e1 = expf(s1 - m);
    float fgv = e1 / (e0 + e1);

    int ri = a / 3, si = a - ri * 3;
    float hh = 16.f * scales[si] * sqrtf(ratios[ri]);
    float ww = 16.f * scales[si] * sqrtf(1.0f / ratios[ri]);
    float by1 = 8.f - hh * 0.5f, bx1 = 8.f - ww * 0.5f;
    float by2 = 8.f + hh * 0.5f, bx2 = 8.f + ww * 0.5f;
    float ay1 = yy * 16.f + by1, ax1 = xx * 16.f + bx1;
    float ay2 = yy * 16.f + by2, ax2 = xx * 16.f + bx2;
    if (img == 0) {
      float* ao = anchors_out + ((size_t)p_loc * 9 + a) * 4;
      ao[0] = ay1; ao[1] = ax1; ao[2] = ay2; ao[3] = ax2;
    }
    float dy = lv.x, dx = lv.y, dh = lv.z, dw = lv.w;
    float ah2 = ay2 - ay1, aw2 = ax2 - ax1;
    float acy = ay1 + 0.5f * ah2, acx = ax1 + 0.5f * aw2;
    float cy = dy * ah2 + acy, cx = dx * aw2 + acx;
    float hb = expf(dh) * ah2, wb = expf(dw) * aw2;
    float y1 = fminf(fmaxf(cy - 0.5f * hb, 0.f), imh);
    float x1 = fminf(fmaxf(cx - 0.5f * wb, 0.f), imw);
    float y2 = fminf(fmaxf(cy + 0.5f * hb, 0.f), imh);
    float x2 = fminf(fmaxf(cx + 0.5f * wb, 0.f), imw);
    bool valid = ((y2 - y1) >= 16.0f) && ((x2 - x1) >= 16.0f);
    float s = valid ? fgv : -__builtin_inff();
    boxes[abase + a] = make_float4(y1, x1, y2, x2);
    unsigned int fb = __float_as_uint(s);
    unsigned int mono = (fb & 0x80000000u) ? ~fb : (fb | 0x80000000u);
    unsigned int ii = (unsigned int)(p_loc * 9 + a);
    keys[abase + a] = (((unsigned long long)mono) << 32) | (unsigned int)(~ii);
  }
}

// ---------------- K4: per-image exact top-3000 (sorted desc), R12-verified ------------
__global__ __launch_bounds__(1024) void k4_select(
    const unsigned long long* __restrict__ keys, const float4* __restrict__ boxes,
    float4* __restrict__ sboxes, unsigned int* __restrict__ sfin) {
  const int n = blockIdx.x, tid = threadIdx.x;
  const int lane = tid & 63, wv = tid >> 6;          // 16 waves
  const unsigned long long* kk = keys + (size_t)n * NANCH;
  __shared__ unsigned int hist[2048];
  __shared__ unsigned int wsum[16];
  __shared__ unsigned long long sb[4096];
  __shared__ int selb;
  __shared__ unsigned int cnt;
  unsigned long long prefix = 0ull;
  int need = PRE_NMS_N;
  const int shifts[6] = {53, 42, 31, 20, 10, 0};
  const int widths[6] = {11, 11, 11, 11, 10, 10};
  for (int rd = 0; rd < 6; ++rd) {
    const int s = shifts[rd], w = widths[rd];
    const int hib = s + w;
    for (int b = tid; b < 2048; b += 1024) hist[b] = 0u;
    __syncthreads();
    if (rd == 0) {
      for (int i = tid; i < NANCH; i += 1024) {
        unsigned long long key = kk[i];
        unsigned int bin = (unsigned int)((key >> s) & ((1u << w) - 1u));
        unsigned long long act = ~0ull;
        while (act) {
          int leader = __builtin_ctzll(act);
          unsigned int lb = (unsigned int)__shfl((int)bin, leader);
          bool same = (bin == lb);
          unsigned long long mm = __ballot(same);
          if (lane == leader) atomicAdd(&hist[lb], (unsigned int)__popcll(mm));
          act &= ~mm;
        }
      }
    } else {
      for (int i = tid; i < NANCH; i += 1024) {
        unsigned long long key = kk[i];
        bool match = ((key ^ prefix) >> hib) == 0ull;
        if (match)
          atomicAdd(&hist[(unsigned)((key >> s) & ((1u << w) - 1u))], 1u);
      }
    }
    __syncthreads();
    {
      const int base = wv * 128;
      unsigned int h0 = hist[base + 2 * lane];
      unsigned int h1 = hist[base + 2 * lane + 1];
      unsigned int x = h0 + h1;
      #pragma unroll
      for (int off2 = 1; off2 < 64; off2 <<= 1) {
        unsigned int v = __shfl_down(x, off2);
        x += (lane + off2 < 64) ? v : 0u;
      }
      if (lane == 0) wsum[wv] = x;            // chunk total
      __syncthreads();
      unsigned int offc = 0u;
      for (int w2 = wv + 1; w2 < 16; ++w2) offc += wsum[w2];
      hist[base + 2 * lane] = x + offc;
      hist[base + 2 * lane + 1] = x - h0 + offc;
      __syncthreads();
    }
    const int nb = 1 << w;
    for (int b = tid; b < nb; b += 1024) {
      unsigned int sv = hist[b];
      unsigned int nxt = (b + 1 < 2048) ? hist[b + 1] : 0u;
      if (sv >= (unsigned)need && nxt < (unsigned)need) selb = b;
    }
    __syncthreads();
    int bstar = selb;
    unsigned int cgt = (bstar + 1 < 2048) ? hist[bstar + 1] : 0u;
    unsigned int inbin = hist[bstar] - cgt;      // keys in the pivot bin
    need -= (int)cgt;
    prefix |= ((unsigned long long)bstar) << s;
    __syncthreads();
    if (inbin == (unsigned)need) break;          // exact: identical selection set
    if ((unsigned)(PRE_NMS_N - need) + inbin <= 4096u) break;   // superset fits sb
  }
  if (tid == 0) cnt = 0u;
  __syncthreads();
  for (int i = tid; i < NANCH; i += 1024) {
    unsigned long long key = kk[i];
    if (key >= prefix) {
      unsigned int pos = atomicAdd(&cnt, 1u);
      if (pos < 4096u) sb[pos] = ~key;
    }
  }
  __syncthreads();
  unsigned int c0 = cnt;
  for (int i = tid; i < 4096; i += 1024)
    if (i >= (int)c0) sb[i] = 0xFFFFFFFFFFFFFFFFull;
  __syncthreads();
  for (int k2 = 2; k2 <= 4096; k2 <<= 1) {
    for (int j = k2 >> 1; j > 0; j >>= 1) {
      for (int t = tid; t < 2048; t += 1024) {
        int i = ((t & ~(j - 1)) << 1) | (t & (j - 1));
        int pp = i + j;
        bool up = ((i & k2) == 0);
        unsigned long long va = sb[i], vb = sb[pp];
        bool sw = up ? (va > vb) : (va < vb);
        if (sw) { sb[i] = vb; sb[pp] = va; }
      }
      __syncthreads();
    }
  }
  const float4* bx = boxes + (size_t)n * NANCH;
  for (int r = tid; r < PRE_NMS_N; r += 1024) {
    unsigned long long key = ~sb[r];
    unsigned int idx = ~((unsigned int)(key & 0xFFFFFFFFull));
    sboxes[(size_t)n * PRE_NMS_N + r] = bx[idx];
    unsigned int hi32 = (unsigned int)(key >> 32);
    sfin[n * PRE_NMS_N + r] = (hi32 > 0x007FFFFFu) ? 1u : 0u;
  }
}

// ---------------- K5: suppression bitmask, pair-per-wave (uniform load) ---------------
__global__ __launch_bounds__(256) void k5_mask(
    const float4* __restrict__ sboxes, unsigned long long* __restrict__ mask) {
  const int n = blockIdx.y;
  const int wv = threadIdx.x >> 6, lane = threadIdx.x & 63;
  const int pid = blockIdx.x * 4 + wv;
  if (pid >= NPAIR) return;
  int c = 0, k = pid;
  while (k >= NWORD - c) { k -= NWORD - c; ++c; }
  const int wd = c + k;
  __shared__ float sA[4][64][5];
  const int j = wd * 64 + lane;
  float4 bj = sboxes[(size_t)n * PRE_NMS_N + ((j < PRE_NMS_N) ? j : 0)];
  const float aj = (bj.z - bj.x) * (bj.w - bj.y);
  const int ig = c * 64 + lane;
  float4 bi = sboxes[(size_t)n * PRE_NMS_N + ((ig < PRE_NMS_N) ? ig : 0)];
  sA[wv][lane][0] = bi.x; sA[wv][lane][1] = bi.y;
  sA[wv][lane][2] = bi.z; sA[wv][lane][3] = bi.w;
  sA[wv][lane][4] = (bi.z - bi.x) * (bi.w - bi.y);
  unsigned long long* mrow = mask + ((size_t)n * PRE_NMS_N + c * 64) * NWORD + wd;
  const int nrow = (c == NWORD - 1) ? (PRE_NMS_N - c * 64) : 64;
  for (int il = 0; il < nrow; ++il) {
    float iy1 = sA[wv][il][0], ix1 = sA[wv][il][1];
    float iy2 = sA[wv][il][2], ix2 = sA[wv][il][3], ia = sA[wv][il][4];
    float y1 = fmaxf(iy1, bj.x), x1 = fmaxf(ix1, bj.y);
    float y2 = fminf(iy2, bj.z), x2 = fminf(ix2, bj.w);
    float inter = fmaxf(y2 - y1, 0.f) * fmaxf(x2 - x1, 0.f);
    float uni = ia + aj - inter;
    float iou = (uni > 0.f) ? inter / uni : 0.f;
    bool pr = (j < PRE_NMS_N) && (iou > 0.7f);
    unsigned long long bits = __ballot(pr);
    if (lane == 0) mrow[(size_t)il * NWORD] = bits;
  }
}

// ---------------- K6: greedy NMS — R13: single-wave, barrier-free main loop -----------
// Everything k6 does fits one wave: decision chain already ran in 64 lanes; the running
// suppression R lives as lane-w-holds-word-w registers (readlane broadcast for R[c]);
// OR phase = serial over kept bits, lanes parallel over words (register OR, no atomics);
// chunk slabs (64x47 u64, contiguous in global AND LDS) prefetch via global_load_lds
// with explicit vmcnt(0) drains. stopc/totKF are lane-uniform scalars. One final
// __syncthreads before the epilogue for keepW LDS visibility. Semantics identical
// to R7 (decision, early exit, epilogue all unchanged).
__global__ __launch_bounds__(64) void k6_nms(
    const unsigned long long* __restrict__ mask, const float4* __restrict__ sboxes,
    const unsigned int* __restrict__ sfin,
    float* __restrict__ out_rois, float* __restrict__ out_valid) {
  const int n = blockIdx.x, lane = threadIdx.x;
  const unsigned long long* M = mask + (size_t)n * PRE_NMS_N * NWORD;
  __shared__ __align__(16) unsigned long long rows[2][64][NWORD];
  __shared__ unsigned long long keepW[NWORD];

  // initial slab: chunk 0 (rows 0..63), 64*47*8B = 24064B = 1504 x 16B units
  {
    const char* src = (const char*)M;
    char* dst = (char*)&rows[0][0][0];
    for (int u = 0; u < 24; ++u) {
      int idx = u * 64 + lane;
      if (idx < 1504) gl_lds16(src + idx * 16, dst + idx * 16);
    }
  }
  asm volatile("s_waitcnt vmcnt(0)" ::: "memory");
  __builtin_amdgcn_sched_barrier(0);

  unsigned long long Rw = 0ull;   // lane w holds suppression word w (w < NWORD)
  int totKF = 0;
  int stopc = NWORD;
  int buf = 0;
  for (int c = 0; c < NWORD; ++c) {
    const int nIt = (c == NWORD - 1) ? (PRE_NMS_N - c * 64) : 64;
    const bool hasNext = (c + 1 < NWORD);
    if (hasNext) {
      const int i1 = (c + 1) * 64;
      const int nrows = (i1 + 64 <= PRE_NMS_N) ? 64 : (PRE_NMS_N - i1);
      const int units = (nrows * NWORD) >> 1;          // 16B units (nrows even)
      const char* src = (const char*)(M + (size_t)i1 * NWORD);
      char* dst = (char*)&rows[buf ^ 1][0][0];
      for (int u = 0; u < 24; ++u) {
        int idx = u * 64 + lane;
        if (idx < units) gl_lds16(src + idx * 16, dst + idx * 16);
      }
    }
    // serial diagonal decision (all lanes lockstep, readlane broadcasts)
    unsigned long long Dcur = rows[buf][lane][c];
    unsigned long long rem = rdlane64(Rw, c);
    unsigned long long und = ~rem;
    if (nIt < 64) und &= ((1ull << nIt) - 1ull);
    unsigned long long kept = 0ull;
    while (und) {
      int b = __builtin_ctzll(und);
      kept |= (1ull << b);
      unsigned long long db = rdlane64(Dcur, b);
      und &= ~db;
      und &= ~(1ull << b);
    }
    // fin mask for this chunk (uniform via ballot)
    {
      int i = c * 64 + lane;
      int f = (i < PRE_NMS_N) ? (sfin[n * PRE_NMS_N + i] ? 1 : 0) : 0;
      unsigned long long fM = __ballot(f);
      totKF += (int)__popcll(kept & fM);
    }
    if (lane == 0) keepW[c] = kept;
    if (totKF >= POST_NMS_N && stopc == NWORD) stopc = c;
    if (stopc <= c) break;                  // uniform
    // OR phase: serial over kept bits, lanes parallel over words
    {
      unsigned long long kk2 = kept;
      const bool upd = (lane > c) && (lane < NWORD);
      while (kk2) {
        int b = __builtin_ctzll(kk2); kk2 &= kk2 - 1ull;
        unsigned long long v = rows[buf][b][lane];
        if (upd) Rw |= v;
      }
    }
    if (hasNext) {
      asm volatile("s_waitcnt vmcnt(0)" ::: "memory");
      __builtin_amdgcn_sched_barrier(0);
    }
    buf ^= 1;
  }
  asm volatile("s_waitcnt vmcnt(0)" ::: "memory");
  __syncthreads();                           // keepW visibility for epilogue

  {
    const int cstop = stopc;                 // last valid chunk (NWORD if no stop)
    const unsigned int* fin = sfin + n * PRE_NMS_N;
    int running = 0;
    for (int c = 0; c < NWORD && c <= cstop; ++c) {
      int i = c * 64 + lane;
      unsigned long long kw = keepW[c];
      int kf = 0;
      if (i < PRE_NMS_N) kf = (int)((kw >> lane) & 1ull) & (fin[i] ? 1 : 0);
      unsigned long long m = __ballot(kf);
      if (kf) {
        int r = running + __popcll(m & ((1ull << lane) - 1ull));
        if (r < POST_NMS_N) {
          float4 b4 = sboxes[(size_t)n * PRE_NMS_N + i];
          float* o = out_rois + (size_t)(n * POST_NMS_N + r) * 4;
          o[0] = b4.x; o[1] = b4.y; o[2] = b4.z; o[3] = b4.w;
          out_valid[n * POST_NMS_N + r] = 1.0f;
        }
      }
      running += __popcll(m);
    }
    int keptTotal = running;
    if (keptTotal < POST_NMS_N) {            // only reachable when cstop==NWORD
      int runN = 0;
      for (int c = 0; c < NWORD && keptTotal + runN < POST_NMS_N; ++c) {
        int i = c * 64 + lane;
        unsigned long long kw = keepW[c];
        int nf = 0;
        if (i < PRE_NMS_N) nf = !(((kw >> lane) & 1ull) && fin[i]);
        unsigned long long m = __ballot(nf);
        if (nf) {
          int r = keptTotal + runN + __popcll(m & ((1ull << lane) - 1ull));
          if (r < POST_NMS_N) {
            float* o = out_rois + (size_t)(n * POST_NMS_N + r) * 4;
            o[0] = 0.f; o[1] = 0.f; o[2] = 0.f; o[3] = 0.f;
            out_valid[n * POST_NMS_N + r] = 0.0f;
          }
        }
        runN += __popcll(m);
      }
    }
  }
}

extern "C" void kernel_launch(void* const* d_in, const int* in_sizes, int n_in,
                              void* d_out, int out_size, void* d_ws, size_t ws_size,
                              hipStream_t stream) {
  const float* x  = (const float*)d_in[0];
  const float* W1 = (const float*)d_in[1];
  const float* b1 = (const float*)d_in[2];
  const float* Ws = (const float*)d_in[3];
  const float* bs = (const float*)d_in[4];
  const float* Wl = (const float*)d_in[5];
  const float* bl = (const float*)d_in[6];
  const int* ihp  = (const int*)d_in[7];
  const int* iwp  = (const int*)d_in[8];

  float* out = (float*)d_out;
  float* o_locs   = out;
  float* o_scores = out + OFF_SCORES;
  float* o_rois   = out + OFF_ROIS;
  float* o_valid  = out + OFF_VALID;
  float* o_anch   = out + OFF_ANCH;

  char* ws = (char*)d_ws;
  const size_t OFF_WTH = 0;                  // 4,718,592
  const size_t OFF_WTL = 4718592;            // 4,718,592
  const size_t OFF_WHD = 9437184;            // head weights hi/lo (ex-fg region)
  const size_t OFF_DYN = 11796480;           // xh | xl | h (nipp images each)

  const size_t PER_IMG = 4460544ull * 2 + 8388608ull;   // xh + xl + h = 17,309,696
  int nipp;
  if (ws_size >= OFF_DYN + 4 * PER_IMG) nipp = 4;
  else if (ws_size >= OFF_DYN + 2 * PER_IMG) nipp = 2;
  else nipp = 1;
  const int nph = N_IMG / nipp;

  _Float16* wth  = (_Float16*)(ws + OFF_WTH);
  _Float16* wtl  = (_Float16*)(ws + OFF_WTL);
  _Float16* whdh = (_Float16*)(ws + OFF_WHD);            // 64*512*2 = 65,536
  _Float16* whdl = (_Float16*)(ws + OFF_WHD + 65536);
  _Float16* xh   = (_Float16*)(ws + OFF_DYN);
  _Float16* xl   = (_Float16*)(ws + OFF_DYN + (size_t)nipp * 4460544);
  float* h       = (float*)(ws + OFF_DYN + (size_t)nipp * 8921088);

  float4* boxes            = (float4*)(ws + OFF_DYN);
  unsigned long long* keys = (unsigned long long*)(ws + OFF_DYN + 2359296);
  float4* sboxes           = (float4*)(ws + OFF_DYN + 3538944);
  unsigned int* sfin       = (unsigned int*)(ws + OFF_DYN + 3730944);
  unsigned long long* mask = (unsigned long long*)(ws + OFF_DYN + 3778944);

  if (nph > 1) {
    size_t tail = OFF_DYN + (size_t)nipp * PER_IMG;
    boxes  = (float4*)(ws + tail);
    keys   = (unsigned long long*)(ws + tail + 2359296);
    sboxes = (float4*)(ws + tail + 3538944);
    sfin   = (unsigned int*)(ws + tail + 3730944);
    mask   = (unsigned long long*)(ws + tail + 3778944);
  }

  k0wh_convert<<<272, 256, 0, stream>>>(W1, wth, wtl, Wl, Ws, whdh, whdl);

  for (int ph = 0; ph < nph; ++ph) {
    int img0 = ph * nipp;
    k0x_convert<<<dim3(69, 8, nipp), 256, 0, stream>>>(x, xh, xl, img0);
    k1_gemm<<<dim3(4, nipp * 32), 256, 0, stream>>>(xh, xl, wth, wtl, b1, h);
    k2m_heads<<<dim3(nipp * 32), 256, 0, stream>>>(h, whdh, whdl, bl, bs,
                                                   o_locs, o_scores, img0,
                                                   ihp, iwp, o_anch, boxes, keys);
  }

  k4_select<<<4, 1024, 0, stream>>>(keys, boxes, sboxes, sfin);
  k5_mask<<<dim3((NPAIR + 3) / 4, 4), 256, 0, stream>>>(sboxes, mask);
  k6_nms<<<4, 64, 0, stream>>>(mask, sboxes, sfin, o_rois, o_valid);
}

// Round 14
// 504.757 us; speedup vs baseline: 1.0304x; 1.0304x over previous
//
#include <hip/hip_runtime.h>
#include <hip/hip_bf16.h>
#include <math.h>

#define N_IMG 4
#define CIN 512
#define NANCH 36864          // 64*64*9
#define PRE_NMS_N 3000
#define POST_NMS_N 300
#define NWORD 47             // ceil(3000/64)
#define NPAIR 1128           // NWORD*(NWORD+1)/2
#define PPX 4356             // 66*66 padded pixels

// out layout (floats)
#define OFF_SCORES 589824
#define OFF_ROIS   884736
#define OFF_VALID  889536
#define OFF_ANCH   890736

typedef _Float16 f16x8 __attribute__((ext_vector_type(8)));
typedef float f32x4 __attribute__((ext_vector_type(4)));

__device__ __forceinline__ int swz(int p) { return (p + (p >> 2)) & 3; }

__device__ __forceinline__ unsigned long long rdlane64(unsigned long long v, int l) {
  unsigned int lo = (unsigned int)__builtin_amdgcn_readlane((int)(unsigned int)v, l);
  unsigned int hi = (unsigned int)__builtin_amdgcn_readlane((int)(unsigned int)(v >> 32), l);
  return (((unsigned long long)hi) << 32) | lo;
}

// ---------------- K0wh: W1 split (x64) + head-weight split (x64), fused launch --------
__global__ __launch_bounds__(256) void k0wh_convert(
    const float* __restrict__ W1, _Float16* __restrict__ wth, _Float16* __restrict__ wtl,
    const float* __restrict__ Wl, const float* __restrict__ Ws,
    _Float16* __restrict__ whdh, _Float16* __restrict__ whdl) {
  const int bx = blockIdx.x;
  if (bx < 144) {
    const int tap = bx % 9, co0 = (bx / 9) * 32;
    for (int idx = threadIdx.x; idx < 32 * 512; idx += 256) {
      int col = idx >> 9, ci = idx & 511;
      float v = W1[(size_t)(co0 + col) * 4608 + ci * 9 + tap] * 64.0f;
      _Float16 hi = (_Float16)v;
      float lo = v - (float)hi;
      size_t o = ((size_t)(tap * 512 + co0 + col) << 9) + ci;
      wth[o] = hi; wtl[o] = (_Float16)lo;
    }
  } else {
    int idx = (bx - 144) * 256 + threadIdx.x;
    if (idx < 64 * 512) {
      int ch = idx >> 9, k = idx & 511;
      float v = 0.f;
      if (ch < 36) v = Wl[ch * 512 + k];
      else if (ch < 54) v = Ws[(ch - 36) * 512 + k];
      v *= 64.0f;
      _Float16 hi = (_Float16)v;
      float lo = v - (float)hi;
      whdh[idx] = hi; whdl[idx] = (_Float16)lo;
    }
  }
}

// ---------------- K0x: x [ci][64x64] -> padded xh/xl [img_l][66*66][512] f16 split ----
__global__ __launch_bounds__(256) void k0x_convert(
    const float* __restrict__ x, _Float16* __restrict__ xh, _Float16* __restrict__ xl,
    int img0) {
  const int bx = blockIdx.x, ci0 = blockIdx.y * 64;
  const int img_l = blockIdx.z;
  const int img = img0 + img_l;
  const size_t sbase = (size_t)img_l * PPX;
  const int tid = threadIdx.x;
  if (bx < 64) {
    __shared__ float t[64][65];
    const float* xp = x + ((size_t)img * 512 + ci0) * 4096 + bx * 64;
    for (int idx = tid; idx < 4096; idx += 256) {
      int ci_l = idx >> 6, col = idx & 63;
      t[ci_l][col] = xp[(size_t)ci_l * 4096 + col];
    }
    __syncthreads();
    for (int idx = tid; idx < 4096; idx += 256) {
      int col = idx >> 6, ci_l = idx & 63;
      float v = t[ci_l][col];
      _Float16 hi = (_Float16)v;
      float lo = v - (float)hi;
      size_t o = ((sbase + (size_t)(bx + 1) * 66 + col + 1) << 9) + ci0 + ci_l;
      xh[o] = hi; xl[o] = (_Float16)lo;
    }
  } else {
    for (int tt = tid; tt < 52 * 64; tt += 256) {
      int pl = tt >> 6, ci_l = tt & 63;
      int p = (bx - 64) * 52 + pl;
      if (p < 260) {
        int pp;
        if (p < 66) pp = p;
        else if (p < 132) pp = 65 * 66 + (p - 66);
        else if (p < 196) pp = (p - 132 + 1) * 66;
        else pp = (p - 196 + 1) * 66 + 65;
        size_t o = ((sbase + pp) << 9) + ci0 + ci_l;
        xh[o] = (_Float16)0.f; xl[o] = (_Float16)0.f;
      }
    }
  }
}

// ---------------- K1: conv3x3 MFMA implicit GEMM, 128x128 block tile ------------------
// The R0 verified form (merged K, register staging, LDS-write after MFMA, dist-1
// prefetch). Alternatives HW-refuted: R3 global-B fragments (352us), R10
// global_load_lds staging (322us). Measured local optimum: ~252us, MfmaUtil ~42%.
__global__ __launch_bounds__(256, 2) void k1_gemm(
    const _Float16* __restrict__ xh, const _Float16* __restrict__ xl,
    const _Float16* __restrict__ wth, const _Float16* __restrict__ wtl,
    const float* __restrict__ b1, float* __restrict__ h_out) {
  const int tid = threadIdx.x;
  const int co0 = blockIdx.x * 128;
  const int px0 = blockIdx.y * 128;          // linear px across nipp images
  const int img_l = px0 >> 12;
  const int y0 = (px0 & 4095) >> 6;

  __shared__ __align__(16) _Float16 AsL[4][4096];   // [buf*2+hl][128px x 32ci]
  __shared__ __align__(16) _Float16 BsL[4][4096];   // [buf*2+hl][128co x 32ci]

  const int lane = tid & 63, q = lane >> 4, lr = lane & 15;
  const int wid = tid >> 6, wm = wid & 1, wn = wid >> 1;

  int abase[2], bbase[2];
  #pragma unroll
  for (int it = 0; it < 2; ++it) {
    int s = it * 256 + tid;
    int pxl = s >> 2, cpos = s & 3;
    int c = cpos ^ swz(pxl);
    int row = pxl >> 6, xcol = pxl & 63;
    abase[it] = ((img_l * PPX + (y0 + row) * 66 + xcol) << 9) + c * 8;
    int bcol = s >> 2;
    int bc = (s & 3) ^ swz(bcol);
    bbase[it] = ((co0 + bcol) << 9) + bc * 8;
  }

  const int DD[9] = {0, 1, 2, 66, 67, 68, 132, 133, 134};

  f32x4 acc[4][4] = {};
  float4 rah[2], ral[2], rbh[2], rbl[2];

  #pragma unroll
  for (int it = 0; it < 2; ++it) {
    rah[it] = *(const float4*)(xh + abase[it]);
    ral[it] = *(const float4*)(xl + abase[it]);
    rbh[it] = *(const float4*)(wth + bbase[it]);
    rbl[it] = *(const float4*)(wtl + bbase[it]);
  }
  #pragma unroll
  for (int it = 0; it < 2; ++it) {
    *(float4*)&AsL[0][(it * 256 + tid) * 8] = rah[it];
    *(float4*)&AsL[1][(it * 256 + tid) * 8] = ral[it];
    *(float4*)&BsL[0][(it * 256 + tid) * 8] = rbh[it];
    *(float4*)&BsL[1][(it * 256 + tid) * 8] = rbl[it];
  }

  int tap = 0, cb = 0;   // tap fastest (cb-outer)
  for (int t = 0; t < 144; ++t) {
    __syncthreads();
    const int buf = t & 1;
    if (t < 143) {
      int tapn = tap + 1, cbn = cb;
      if (tapn == 9) { tapn = 0; cbn = cb + 1; }
      int ad = (DD[tapn] << 9) + cbn * 32;
      int bd = tapn * 262144 + cbn * 32;
      #pragma unroll
      for (int it = 0; it < 2; ++it) {
        rah[it] = *(const float4*)(xh + abase[it] + ad);
        ral[it] = *(const float4*)(xl + abase[it] + ad);
        rbh[it] = *(const float4*)(wth + bbase[it] + bd);
        rbl[it] = *(const float4*)(wtl + bbase[it] + bd);
      }
    }
    f16x8 ah[4], al[4], bh[4], bl[4];
    #pragma unroll
    for (int mi = 0; mi < 4; ++mi) {
      int pxl = wm * 64 + mi * 16 + lr;
      int cpr = q ^ swz(pxl);
      ah[mi] = *(const f16x8*)&AsL[buf * 2 + 0][pxl * 32 + cpr * 8];
      al[mi] = *(const f16x8*)&AsL[buf * 2 + 1][pxl * 32 + cpr * 8];
    }
    #pragma unroll
    for (int ni = 0; ni < 4; ++ni) {
      int col = wn * 64 + ni * 16 + lr;
      int cpr = q ^ swz(col);
      bh[ni] = *(const f16x8*)&BsL[buf * 2 + 0][col * 32 + cpr * 8];
      bl[ni] = *(const f16x8*)&BsL[buf * 2 + 1][col * 32 + cpr * 8];
    }
    #pragma unroll
    for (int mi = 0; mi < 4; ++mi)
      #pragma unroll
      for (int ni = 0; ni < 4; ++ni) {
        acc[mi][ni] = __builtin_amdgcn_mfma_f32_16x16x32_f16(ah[mi], bh[ni], acc[mi][ni], 0, 0, 0);
        acc[mi][ni] = __builtin_amdgcn_mfma_f32_16x16x32_f16(ah[mi], bl[ni], acc[mi][ni], 0, 0, 0);
        acc[mi][ni] = __builtin_amdgcn_mfma_f32_16x16x32_f16(al[mi], bh[ni], acc[mi][ni], 0, 0, 0);
      }
    if (t < 143) {
      int nb = (t + 1) & 1;
      #pragma unroll
      for (int it = 0; it < 2; ++it) {
        *(float4*)&AsL[nb * 2 + 0][(it * 256 + tid) * 8] = rah[it];
        *(float4*)&AsL[nb * 2 + 1][(it * 256 + tid) * 8] = ral[it];
        *(float4*)&BsL[nb * 2 + 0][(it * 256 + tid) * 8] = rbh[it];
        *(float4*)&BsL[nb * 2 + 1][(it * 256 + tid) * 8] = rbl[it];
      }
    }
    ++tap;
    if (tap == 9) { tap = 0; ++cb; }
  }

  float bb[4];
  #pragma unroll
  for (int ni = 0; ni < 4; ++ni) bb[ni] = b1[co0 + wn * 64 + ni * 16 + lr];
  #pragma unroll
  for (int mi = 0; mi < 4; ++mi)
    #pragma unroll
    for (int ni = 0; ni < 4; ++ni)
      #pragma unroll
      for (int rr = 0; rr < 4; ++rr) {
        int pxl = wm * 64 + mi * 16 + q * 4 + rr;
        int co = co0 + wn * 64 + ni * 16 + lr;
        float v = acc[mi][ni][rr] * 0.015625f + bb[ni];
        h_out[((size_t)(px0 + pxl) << 9) + co] = fmaxf(v, 0.f);
      }
}

// ---------------- K2m: heads as MFMA implicit GEMM + fused decode (R8) ----------------
__global__ __launch_bounds__(256, 1) void k2m_heads(
    const float* __restrict__ h,
    const _Float16* __restrict__ whdh, const _Float16* __restrict__ whdl,
    const float* __restrict__ bl, const float* __restrict__ bs,
    float* __restrict__ rpn_locs, float* __restrict__ rpn_scores,
    int img0, const int* __restrict__ ihp, const int* __restrict__ iwp,
    float* __restrict__ anchors_out, float4* __restrict__ boxes,
    unsigned long long* __restrict__ keys) {
  const int tid = threadIdx.x;
  const int px0 = blockIdx.x * 128;          // linear px across nipp images

  __shared__ __align__(16) _Float16 As[4][4096];   // [buf*2+hl][128px x 32k]
  __shared__ __align__(16) _Float16 Bs[4][2048];   // [buf*2+hl][64ch x 32k]
  __shared__ float Cs[128][68];                    // +4 pad

  const int lane = tid & 63, q = lane >> 4, lr = lane & 15;
  const int wid = tid >> 6, wm = wid & 1, wn = wid >> 1;

  int apx[2], ac[2];
  #pragma unroll
  for (int it = 0; it < 2; ++it) {
    int s = it * 256 + tid;
    apx[it] = s >> 2;
    ac[it] = (s & 3) ^ swz(s >> 2);
  }
  const int bcol = tid >> 2, bc = (tid & 3) ^ swz(tid >> 2);

  f32x4 acc[4][2] = {};
  f16x8 rahh[2], rahl[2], rbhh, rbhl;

  // prologue: tile 0
  #pragma unroll
  for (int it = 0; it < 2; ++it) {
    const float* src = h + ((size_t)(px0 + apx[it]) << 9) + ac[it] * 8;
    float4 v0 = *(const float4*)(src);
    float4 v1 = *(const float4*)(src + 4);
    float vv[8] = {v0.x, v0.y, v0.z, v0.w, v1.x, v1.y, v1.z, v1.w};
    f16x8 hi8, lo8;
    #pragma unroll
    for (int e = 0; e < 8; ++e) {
      _Float16 hh = (_Float16)vv[e];
      hi8[e] = hh; lo8[e] = (_Float16)(vv[e] - (float)hh);
    }
    rahh[it] = hi8; rahl[it] = lo8;
  }
  rbhh = *(const f16x8*)(whdh + bcol * 512 + bc * 8);
  rbhl = *(const f16x8*)(whdl + bcol * 512 + bc * 8);
  #pragma unroll
  for (int it = 0; it < 2; ++it) {
    *(f16x8*)&As[0][(it * 256 + tid) * 8] = rahh[it];
    *(f16x8*)&As[1][(it * 256 + tid) * 8] = rahl[it];
  }
  *(f16x8*)&Bs[0][tid * 8] = rbhh;
  *(f16x8*)&Bs[1][tid * 8] = rbhl;

  for (int t = 0; t < 16; ++t) {
    __syncthreads();
    const int buf = t & 1;
    if (t < 15) {
      const int kn = (t + 1) * 32;
      #pragma unroll
      for (int it = 0; it < 2; ++it) {
        const float* src = h + ((size_t)(px0 + apx[it]) << 9) + kn + ac[it] * 8;
        float4 v0 = *(const float4*)(src);
        float4 v1 = *(const float4*)(src + 4);
        float vv[8] = {v0.x, v0.y, v0.z, v0.w, v1.x, v1.y, v1.z, v1.w};
        f16x8 hi8, lo8;
        #pragma unroll
        for (int e = 0; e < 8; ++e) {
          _Float16 hh = (_Float16)vv[e];
          hi8[e] = hh; lo8[e] = (_Float16)(vv[e] - (float)hh);
        }
        rahh[it] = hi8; rahl[it] = lo8;
      }
      rbhh = *(const f16x8*)(whdh + bcol * 512 + kn + bc * 8);
      rbhl = *(const f16x8*)(whdl + bcol * 512 + kn + bc * 8);
    }
    f16x8 ah[4], al[4], bh[2], blo[2];
    #pragma unroll
    for (int mi = 0; mi < 4; ++mi) {
      int pxl = wm * 64 + mi * 16 + lr;
      int cpr = q ^ swz(pxl);
      ah[mi] = *(const f16x8*)&As[buf * 2 + 0][pxl * 32 + cpr * 8];
      al[mi] = *(const f16x8*)&As[buf * 2 + 1][pxl * 32 + cpr * 8];
    }
    #pragma unroll
    for (int ni = 0; ni < 2; ++ni) {
      int col = wn * 32 + ni * 16 + lr;
      int cpr = q ^ swz(col);
      bh[ni]  = *(const f16x8*)&Bs[buf * 2 + 0][col * 32 + cpr * 8];
      blo[ni] = *(const f16x8*)&Bs[buf * 2 + 1][col * 32 + cpr * 8];
    }
    #pragma unroll
    for (int mi = 0; mi < 4; ++mi)
      #pragma unroll
      for (int ni = 0; ni < 2; ++ni) {
        acc[mi][ni] = __builtin_amdgcn_mfma_f32_16x16x32_f16(ah[mi], bh[ni],  acc[mi][ni], 0, 0, 0);
        acc[mi][ni] = __builtin_amdgcn_mfma_f32_16x16x32_f16(ah[mi], blo[ni], acc[mi][ni], 0, 0, 0);
        acc[mi][ni] = __builtin_amdgcn_mfma_f32_16x16x32_f16(al[mi], bh[ni],  acc[mi][ni], 0, 0, 0);
      }
    if (t < 15) {
      int nb = (t + 1) & 1;
      #pragma unroll
      for (int it = 0; it < 2; ++it) {
        *(f16x8*)&As[nb * 2 + 0][(it * 256 + tid) * 8] = rahh[it];
        *(f16x8*)&As[nb * 2 + 1][(it * 256 + tid) * 8] = rahl[it];
      }
      *(f16x8*)&Bs[nb * 2 + 0][tid * 8] = rbhh;
      *(f16x8*)&Bs[nb * 2 + 1][tid * 8] = rbhl;
    }
  }

  // C tile -> LDS with /64 + bias
  #pragma unroll
  for (int mi = 0; mi < 4; ++mi)
    #pragma unroll
    for (int ni = 0; ni < 2; ++ni) {
      int ch = wn * 32 + ni * 16 + lr;
      float bias = (ch < 36) ? bl[ch] : ((ch < 54) ? bs[ch - 36] : 0.f);
      #pragma unroll
      for (int rr = 0; rr < 4; ++rr) {
        int pxl = wm * 64 + mi * 16 + q * 4 + rr;
        Cs[pxl][ch] = acc[mi][ni][rr] * 0.015625f + bias;
      }
    }
  __syncthreads();

  // fused decode epilogue: 128 px x 9 anchors (verbatim math from old k2)
  const float imh = (float)ihp[0], imw = (float)iwp[0];
  const float ratios[3] = {0.5f, 1.0f, 2.0f};
  const float scales[3] = {8.f, 16.f, 32.f};
  for (int t2 = tid; t2 < 128 * 9; t2 += 256) {
    int px_l = t2 / 9, a = t2 - px_l * 9;
    int pxg = px0 + px_l;
    int img = img0 + (pxg >> 12);
    int p_loc = pxg & 4095;
    size_t abase = (size_t)img * NANCH + (size_t)p_loc * 9;
    int yy = p_loc >> 6, xx = p_loc & 63;

    float4 lv; lv.x = Cs[px_l][4 * a]; lv.y = Cs[px_l][4 * a + 1];
    lv.z = Cs[px_l][4 * a + 2]; lv.w = Cs[px_l][4 * a + 3];
    *(float4*)(rpn_locs + (abase + a) * 4) = lv;
    float s0 = Cs[px_l][36 + 2 * a], s1 = Cs[px_l][36 + 2 * a + 1];
    float2 sv; sv.x = s0; sv.y = s1;
    *(float2*)(rpn_scores + (abase + a) * 2) = sv;
    float m = fmaxf(s0, s1);
    float e0 = expf(s0 - m), e1 = expf(s1 - m);
    float fgv = e1 / (e0 + e1);

    int ri = a / 3, si = a - ri * 3;
    float hh = 16.f * scales[si] * sqrtf(ratios[ri]);
    float ww = 16.f * scales[si] * sqrtf(1.0f / ratios[ri]);
    float by1 = 8.f - hh * 0.5f, bx1 = 8.f - ww * 0.5f;
    float by2 = 8.f + hh * 0.5f, bx2 = 8.f + ww * 0.5f;
    float ay1 = yy * 16.f + by1, ax1 = xx * 16.f + bx1;
    float ay2 = yy * 16.f + by2, ax2 = xx * 16.f + bx2;
    if (img == 0) {
      float* ao = anchors_out + ((size_t)p_loc * 9 + a) * 4;
      ao[0] = ay1; ao[1] = ax1; ao[2] = ay2; ao[3] = ax2;
    }
    float dy = lv.x, dx = lv.y, dh = lv.z, dw = lv.w;
    float ah2 = ay2 - ay1, aw2 = ax2 - ax1;
    float acy = ay1 + 0.5f * ah2, acx = ax1 + 0.5f * aw2;
    float cy = dy * ah2 + acy, cx = dx * aw2 + acx;
    float hb = expf(dh) * ah2, wb = expf(dw) * aw2;
    float y1 = fminf(fmaxf(cy - 0.5f * hb, 0.f), imh);
    float x1 = fminf(fmaxf(cx - 0.5f * wb, 0.f), imw);
    float y2 = fminf(fmaxf(cy + 0.5f * hb, 0.f), imh);
    float x2 = fminf(fmaxf(cx + 0.5f * wb, 0.f), imw);
    bool valid = ((y2 - y1) >= 16.0f) && ((x2 - x1) >= 16.0f);
    float s = valid ? fgv : -__builtin_inff();
    boxes[abase + a] = make_float4(y1, x1, y2, x2);
    unsigned int fb = __float_as_uint(s);
    unsigned int mono = (fb & 0x80000000u) ? ~fb : (fb | 0x80000000u);
    unsigned int ii = (unsigned int)(p_loc * 9 + a);
    keys[abase + a] = (((unsigned long long)mono) << 32) | (unsigned int)(~ii);
  }
}

// ---------------- K4: per-image exact top-3000 (sorted desc), R12-verified ------------
__global__ __launch_bounds__(1024) void k4_select(
    const unsigned long long* __restrict__ keys, const float4* __restrict__ boxes,
    float4* __restrict__ sboxes, unsigned int* __restrict__ sfin) {
  const int n = blockIdx.x, tid = threadIdx.x;
  const int lane = tid & 63, wv = tid >> 6;          // 16 waves
  const unsigned long long* kk = keys + (size_t)n * NANCH;
  __shared__ unsigned int hist[2048];
  __shared__ unsigned int wsum[16];
  __shared__ unsigned long long sb[4096];
  __shared__ int selb;
  __shared__ unsigned int cnt;
  unsigned long long prefix = 0ull;
  int need = PRE_NMS_N;
  const int shifts[6] = {53, 42, 31, 20, 10, 0};
  const int widths[6] = {11, 11, 11, 11, 10, 10};
  for (int rd = 0; rd < 6; ++rd) {
    const int s = shifts[rd], w = widths[rd];
    const int hib = s + w;
    for (int b = tid; b < 2048; b += 1024) hist[b] = 0u;
    __syncthreads();
    if (rd == 0) {
      for (int i = tid; i < NANCH; i += 1024) {
        unsigned long long key = kk[i];
        unsigned int bin = (unsigned int)((key >> s) & ((1u << w) - 1u));
        unsigned long long act = ~0ull;
        while (act) {
          int leader = __builtin_ctzll(act);
          unsigned int lb = (unsigned int)__shfl((int)bin, leader);
          bool same = (bin == lb);
          unsigned long long mm = __ballot(same);
          if (lane == leader) atomicAdd(&hist[lb], (unsigned int)__popcll(mm));
          act &= ~mm;
        }
      }
    } else {
      for (int i = tid; i < NANCH; i += 1024) {
        unsigned long long key = kk[i];
        bool match = ((key ^ prefix) >> hib) == 0ull;
        if (match)
          atomicAdd(&hist[(unsigned)((key >> s) & ((1u << w) - 1u))], 1u);
      }
    }
    __syncthreads();
    {
      const int base = wv * 128;
      unsigned int h0 = hist[base + 2 * lane];
      unsigned int h1 = hist[base + 2 * lane + 1];
      unsigned int x = h0 + h1;
      #pragma unroll
      for (int off2 = 1; off2 < 64; off2 <<= 1) {
        unsigned int v = __shfl_down(x, off2);
        x += (lane + off2 < 64) ? v : 0u;
      }
      if (lane == 0) wsum[wv] = x;            // chunk total
      __syncthreads();
      unsigned int offc = 0u;
      for (int w2 = wv + 1; w2 < 16; ++w2) offc += wsum[w2];
      hist[base + 2 * lane] = x + offc;
      hist[base + 2 * lane + 1] = x - h0 + offc;
      __syncthreads();
    }
    const int nb = 1 << w;
    for (int b = tid; b < nb; b += 1024) {
      unsigned int sv = hist[b];
      unsigned int nxt = (b + 1 < 2048) ? hist[b + 1] : 0u;
      if (sv >= (unsigned)need && nxt < (unsigned)need) selb = b;
    }
    __syncthreads();
    int bstar = selb;
    unsigned int cgt = (bstar + 1 < 2048) ? hist[bstar + 1] : 0u;
    unsigned int inbin = hist[bstar] - cgt;      // keys in the pivot bin
    need -= (int)cgt;
    prefix |= ((unsigned long long)bstar) << s;
    __syncthreads();
    if (inbin == (unsigned)need) break;          // exact: identical selection set
    if ((unsigned)(PRE_NMS_N - need) + inbin <= 4096u) break;   // superset fits sb
  }
  if (tid == 0) cnt = 0u;
  __syncthreads();
  for (int i = tid; i < NANCH; i += 1024) {
    unsigned long long key = kk[i];
    if (key >= prefix) {
      unsigned int pos = atomicAdd(&cnt, 1u);
      if (pos < 4096u) sb[pos] = ~key;
    }
  }
  __syncthreads();
  unsigned int c0 = cnt;
  for (int i = tid; i < 4096; i += 1024)
    if (i >= (int)c0) sb[i] = 0xFFFFFFFFFFFFFFFFull;
  __syncthreads();
  for (int k2 = 2; k2 <= 4096; k2 <<= 1) {
    for (int j = k2 >> 1; j > 0; j >>= 1) {
      for (int t = tid; t < 2048; t += 1024) {
        int i = ((t & ~(j - 1)) << 1) | (t & (j - 1));
        int pp = i + j;
        bool up = ((i & k2) == 0);
        unsigned long long va = sb[i], vb = sb[pp];
        bool sw = up ? (va > vb) : (va < vb);
        if (sw) { sb[i] = vb; sb[pp] = va; }
      }
      __syncthreads();
    }
  }
  const float4* bx = boxes + (size_t)n * NANCH;
  for (int r = tid; r < PRE_NMS_N; r += 1024) {
    unsigned long long key = ~sb[r];
    unsigned int idx = ~((unsigned int)(key & 0xFFFFFFFFull));
    sboxes[(size_t)n * PRE_NMS_N + r] = bx[idx];
    unsigned int hi32 = (unsigned int)(key >> 32);
    sfin[n * PRE_NMS_N + r] = (hi32 > 0x007FFFFFu) ? 1u : 0u;
  }
}

// ---------------- K5: suppression bitmask, pair-per-wave (uniform load) ---------------
__global__ __launch_bounds__(256) void k5_mask(
    const float4* __restrict__ sboxes, unsigned long long* __restrict__ mask) {
  const int n = blockIdx.y;
  const int wv = threadIdx.x >> 6, lane = threadIdx.x & 63;
  const int pid = blockIdx.x * 4 + wv;
  if (pid >= NPAIR) return;
  int c = 0, k = pid;
  while (k >= NWORD - c) { k -= NWORD - c; ++c; }
  const int wd = c + k;
  __shared__ float sA[4][64][5];
  const int j = wd * 64 + lane;
  float4 bj = sboxes[(size_t)n * PRE_NMS_N + ((j < PRE_NMS_N) ? j : 0)];
  const float aj = (bj.z - bj.x) * (bj.w - bj.y);
  const int ig = c * 64 + lane;
  float4 bi = sboxes[(size_t)n * PRE_NMS_N + ((ig < PRE_NMS_N) ? ig : 0)];
  sA[wv][lane][0] = bi.x; sA[wv][lane][1] = bi.y;
  sA[wv][lane][2] = bi.z; sA[wv][lane][3] = bi.w;
  sA[wv][lane][4] = (bi.z - bi.x) * (bi.w - bi.y);
  unsigned long long* mrow = mask + ((size_t)n * PRE_NMS_N + c * 64) * NWORD + wd;
  const int nrow = (c == NWORD - 1) ? (PRE_NMS_N - c * 64) : 64;
  for (int il = 0; il < nrow; ++il) {
    float iy1 = sA[wv][il][0], ix1 = sA[wv][il][1];
    float iy2 = sA[wv][il][2], ix2 = sA[wv][il][3], ia = sA[wv][il][4];
    float y1 = fmaxf(iy1, bj.x), x1 = fmaxf(ix1, bj.y);
    float y2 = fminf(iy2, bj.z), x2 = fminf(ix2, bj.w);
    float inter = fmaxf(y2 - y1, 0.f) * fmaxf(x2 - x1, 0.f);
    float uni = ia + aj - inter;
    float iou = (uni > 0.f) ? inter / uni : 0.f;
    bool pr = (j < PRE_NMS_N) && (iou > 0.7f);
    unsigned long long bits = __ballot(pr);
    if (lane == 0) mrow[(size_t)il * NWORD] = bits;
  }
}

// ---------------- K6: chunked greedy NMS — R12-verified (256thr, parallel OR, exit) ---
// R13 single-wave variant regressed (+13us): 4-wave prefetch supplies the MLP that
// hides the chunk-slab HBM/L2 latency; single wave exposed it at every vmcnt drain.
__global__ __launch_bounds__(256) void k6_nms(
    const unsigned long long* __restrict__ mask, const float4* __restrict__ sboxes,
    const unsigned int* __restrict__ sfin,
    float* __restrict__ out_rois, float* __restrict__ out_valid) {
  const int n = blockIdx.x, tid = threadIdx.x;
  const int lane = tid & 63, wvq = tid >> 6;
  const unsigned long long* M = mask + (size_t)n * PRE_NMS_N * NWORD;
  __shared__ unsigned long long rows[2][64][NWORD];
  __shared__ unsigned long long keepW[NWORD];
  __shared__ unsigned long long finM[NWORD];
  __shared__ unsigned long long R[NWORD];     // running suppression (word w)
  __shared__ int klist[64];
  __shared__ int kcnt_sh;
  __shared__ int stopc_sh;

  if (tid == 0) stopc_sh = NWORD;
  for (int w = tid; w < NWORD; w += 256) R[w] = 0ull;

  for (int c = wvq; c < NWORD; c += 4) {
    int i = c * 64 + lane;
    int f = (i < PRE_NMS_N) ? (sfin[n * PRE_NMS_N + i] ? 1 : 0) : 0;
    unsigned long long mb = __ballot(f);
    if (lane == 0) finM[c] = mb;
  }

  #pragma unroll
  for (int j = 0; j < 12; ++j) {
    int idx = j * 256 + tid;
    if (idx < 64 * NWORD) {
      int row = idx / NWORD, w = idx - row * NWORD;
      rows[0][row][w] = M[(size_t)row * NWORD + w];
    }
  }
  __syncthreads();

  int totKF = 0;     // wave0-uniform running kept∧fin count
  for (int c = 0; c < NWORD; ++c) {
    const int buf = c & 1;
    const int nIt = (c == NWORD - 1) ? (PRE_NMS_N - c * 64) : 64;
    unsigned long long pf[12];
    const bool hasNext = (c + 1 < NWORD);
    if (hasNext) {
      const int i1 = (c + 1) * 64;
      #pragma unroll
      for (int j = 0; j < 12; ++j) {
        int idx = j * 256 + tid;
        if (idx < 64 * NWORD) {
          int row = idx / NWORD, w = idx - row * NWORD;
          int gi = i1 + row;
          pf[j] = (gi < PRE_NMS_N) ? M[(size_t)gi * NWORD + w] : 0ull;
        }
      }
    }
    if (tid < 64) {
      unsigned long long Dcur = rows[buf][lane][c];
      unsigned long long rem = R[c];
      unsigned long long und = ~rem;
      if (nIt < 64) und &= ((1ull << nIt) - 1ull);
      unsigned long long kept = 0ull;
      while (und) {
        int b = __builtin_ctzll(und);
        kept |= (1ull << b);
        unsigned long long db = rdlane64(Dcur, b);
        und &= ~db;
        und &= ~(1ull << b);
      }
      totKF += (int)__popcll(kept & finM[c]);
      if (lane == 0) {
        keepW[c] = kept; kcnt_sh = (int)__popcll(kept);
        if (totKF >= POST_NMS_N && stopc_sh == NWORD) stopc_sh = c;
      }
      if ((kept >> lane) & 1ull) {
        int r = (int)__popcll(kept & ((1ull << lane) - 1ull));
        klist[r] = lane;
      }
    }
    __syncthreads();
    if (stopc_sh <= c) break;               // uniform: all threads see same stopc
    {
      const int kc = kcnt_sh;
      const int w0 = c + 1;
      const int nw = NWORD - w0;
      const int tot = kc * nw;
      for (int it2 = tid; it2 < tot; it2 += 256) {
        int ki = it2 / nw, w = w0 + (it2 - ki * nw);
        int b = klist[ki];
        unsigned long long v = rows[buf][b][w];
        if (v) atomicOr(&R[w], v);
      }
    }
    if (hasNext) {
      #pragma unroll
      for (int j = 0; j < 12; ++j) {
        int idx = j * 256 + tid;
        if (idx < 64 * NWORD) {
          int row = idx / NWORD, w = idx - row * NWORD;
          rows[buf ^ 1][row][w] = pf[j];
        }
      }
    }
    __syncthreads();
  }

  if (tid < 64) {
    const int cstop = stopc_sh;              // last valid chunk (NWORD if no stop)
    const unsigned int* fin = sfin + n * PRE_NMS_N;
    int running = 0;
    for (int c = 0; c < NWORD && c <= cstop; ++c) {
      int i = c * 64 + lane;
      unsigned long long kw = keepW[c];
      int kf = 0;
      if (i < PRE_NMS_N) kf = (int)((kw >> lane) & 1ull) & (fin[i] ? 1 : 0);
      unsigned long long m = __ballot(kf);
      if (kf) {
        int r = running + __popcll(m & ((1ull << lane) - 1ull));
        if (r < POST_NMS_N) {
          float4 b4 = sboxes[(size_t)n * PRE_NMS_N + i];
          float* o = out_rois + (size_t)(n * POST_NMS_N + r) * 4;
          o[0] = b4.x; o[1] = b4.y; o[2] = b4.z; o[3] = b4.w;
          out_valid[n * POST_NMS_N + r] = 1.0f;
        }
      }
      running += __popcll(m);
    }
    int keptTotal = running;
    if (keptTotal < POST_NMS_N) {            // only reachable when cstop==NWORD
      int runN = 0;
      for (int c = 0; c < NWORD && keptTotal + runN < POST_NMS_N; ++c) {
        int i = c * 64 + lane;
        unsigned long long kw = keepW[c];
        int nf = 0;
        if (i < PRE_NMS_N) nf = !(((kw >> lane) & 1ull) && fin[i]);
        unsigned long long m = __ballot(nf);
        if (nf) {
          int r = keptTotal + runN + __popcll(m & ((1ull << lane) - 1ull));
          if (r < POST_NMS_N) {
            float* o = out_rois + (size_t)(n * POST_NMS_N + r) * 4;
            o[0] = 0.f; o[1] = 0.f; o[2] = 0.f; o[3] = 0.f;
            out_valid[n * POST_NMS_N + r] = 0.0f;
          }
        }
        runN += __popcll(m);
      }
    }
  }
}

extern "C" void kernel_launch(void* const* d_in, const int* in_sizes, int n_in,
                              void* d_out, int out_size, void* d_ws, size_t ws_size,
                              hipStream_t stream) {
  const float* x  = (const float*)d_in[0];
  const float* W1 = (const float*)d_in[1];
  const float* b1 = (const float*)d_in[2];
  const float* Ws = (const float*)d_in[3];
  const float* bs = (const float*)d_in[4];
  const float* Wl = (const float*)d_in[5];
  const float* bl = (const float*)d_in[6];
  const int* ihp  = (const int*)d_in[7];
  const int* iwp  = (const int*)d_in[8];

  float* out = (float*)d_out;
  float* o_locs   = out;
  float* o_scores = out + OFF_SCORES;
  float* o_rois   = out + OFF_ROIS;
  float* o_valid  = out + OFF_VALID;
  float* o_anch   = out + OFF_ANCH;

  char* ws = (char*)d_ws;
  const size_t OFF_WTH = 0;                  // 4,718,592
  const size_t OFF_WTL = 4718592;            // 4,718,592
  const size_t OFF_WHD = 9437184;            // head weights hi/lo (ex-fg region)
  const size_t OFF_DYN = 11796480;           // xh | xl | h (nipp images each)

  const size_t PER_IMG = 4460544ull * 2 + 8388608ull;   // xh + xl + h = 17,309,696
  int nipp;
  if (ws_size >= OFF_DYN + 4 * PER_IMG) nipp = 4;
  else if (ws_size >= OFF_DYN + 2 * PER_IMG) nipp = 2;
  else nipp = 1;
  const int nph = N_IMG / nipp;

  _Float16* wth  = (_Float16*)(ws + OFF_WTH);
  _Float16* wtl  = (_Float16*)(ws + OFF_WTL);
  _Float16* whdh = (_Float16*)(ws + OFF_WHD);            // 64*512*2 = 65,536
  _Float16* whdl = (_Float16*)(ws + OFF_WHD + 65536);
  _Float16* xh   = (_Float16*)(ws + OFF_DYN);
  _Float16* xl   = (_Float16*)(ws + OFF_DYN + (size_t)nipp * 4460544);
  float* h       = (float*)(ws + OFF_DYN + (size_t)nipp * 8921088);

  float4* boxes            = (float4*)(ws + OFF_DYN);
  unsigned long long* keys = (unsigned long long*)(ws + OFF_DYN + 2359296);
  float4* sboxes           = (float4*)(ws + OFF_DYN + 3538944);
  unsigned int* sfin       = (unsigned int*)(ws + OFF_DYN + 3730944);
  unsigned long long* mask = (unsigned long long*)(ws + OFF_DYN + 3778944);

  if (nph > 1) {
    size_t tail = OFF_DYN + (size_t)nipp * PER_IMG;
    boxes  = (float4*)(ws + tail);
    keys   = (unsigned long long*)(ws + tail + 2359296);
    sboxes = (float4*)(ws + tail + 3538944);
    sfin   = (unsigned int*)(ws + tail + 3730944);
    mask   = (unsigned long long*)(ws + tail + 3778944);
  }

  k0wh_convert<<<272, 256, 0, stream>>>(W1, wth, wtl, Wl, Ws, whdh, whdl);

  for (int ph = 0; ph < nph; ++ph) {
    int img0 = ph * nipp;
    k0x_convert<<<dim3(69, 8, nipp), 256, 0, stream>>>(x, xh, xl, img0);
    k1_gemm<<<dim3(4, nipp * 32), 256, 0, stream>>>(xh, xl, wth, wtl, b1, h);
    k2m_heads<<<dim3(nipp * 32), 256, 0, stream>>>(h, whdh, whdl, bl, bs,
                                                   o_locs, o_scores, img0,
                                                   ihp, iwp, o_anch, boxes, keys);
  }

  k4_select<<<4, 1024, 0, stream>>>(keys, boxes, sboxes, sfin);
  k5_mask<<<dim3((NPAIR + 3) / 4, 4), 256, 0, stream>>>(sboxes, mask);
  k6_nms<<<4, 256, 0, stream>>>(mask, sboxes, sfin, o_rois, o_valid);
}